// Round 7
// baseline (378.026 us; speedup 1.0000x reference)
//
#include <hip/hip_runtime.h>
#include <hip/hip_bf16.h>
#include <hip/hip_fp16.h>
#include <math.h>

// Problem constants (match reference)
#define NN 50000      // nodes
#define NE 800000     // edges (before self loops)
#define DD 128        // feature dim
#define NG 512        // graphs
#define NSA 0.2f      // attention leaky_relu slope
#define NSB 0.01f     // activation leaky_relu slope
#define EPS 1e-16f
#define CAP 63        // real-edge slots per node (+1 implicit self loop); P(deg>63)~1e-20

// ---------------- init: zero padded cursors (one per 64B line) and d_out ----------------
__global__ void init_kernel(int* __restrict__ cursor, float* __restrict__ out) {
    int i = blockIdx.x * 256 + threadIdx.x;
    if (i < NN * 16) cursor[i] = 0;
    if (i < NG * DD) out[i] = 0.f;
}

// GEMM geometry: 64x128 tile, 512 threads, thread-tile 2 rows x 8 cols.
// LDS staging transposed ([k][row]/[k][col]) with XOR swizzle on the column index:
//   c' = c ^ (((k>>2)&3)<<3)  -- kills the 4-way write conflicts (2-way is free),
//   preserves 8-float group contiguity so b64/b128 reads stay aligned.
#define KC 32
#define BM 64
#define XS_LD (BM + 4)     // 68
#define WS_LD (DD + 4)     // 132
#define SWZ(k) ((((k) >> 2) & 3) << 3)

// ---------------- shared gemm body (device inline) ----------------
__device__ __forceinline__ void gemm_body(
        const float* __restrict__ X, const float* __restrict__ W,
        const float* __restrict__ a_src, const float* __restrict__ a_dst,
        __half* __restrict__ H16, float* __restrict__ as_, float* __restrict__ ad_,
        int nrows, int row0,
        float (*xs)[XS_LD], float (*ws)[WS_LD]) {
    int t = threadIdx.x;
    int tx = t & 15;                  // col group: cols tx*8 .. tx*8+7
    int ty = t >> 4;                  // row group: rows ty*2, ty*2+1 (ty 0..31)
    float acc[2][8] = {};

    for (int k0 = 0; k0 < DD; k0 += KC) {
        // stage X tile: 512 float4 items, one per thread
        {
            int r = t >> 3, kq = t & 7;
            float4 v = {0.f, 0.f, 0.f, 0.f};
            int gr = row0 + r;
            if (gr < nrows) v = *(const float4*)&X[(size_t)gr * DD + k0 + kq * 4];
            int rp = r ^ ((kq & 3) << 3);
            xs[kq * 4 + 0][rp] = v.x;
            xs[kq * 4 + 1][rp] = v.y;
            xs[kq * 4 + 2][rp] = v.z;
            xs[kq * 4 + 3][rp] = v.w;
        }
        // stage W tile: 1024 float4 items, two per thread
        #pragma unroll
        for (int p = 0; p < 2; ++p) {
            int i = t + p * 512;
            int d = i >> 3, kq = i & 7;
            float4 v = *(const float4*)&W[(size_t)d * DD + k0 + kq * 4];
            int dp = d ^ ((kq & 3) << 3);
            ws[kq * 4 + 0][dp] = v.x;
            ws[kq * 4 + 1][dp] = v.y;
            ws[kq * 4 + 2][dp] = v.z;
            ws[kq * 4 + 3][dp] = v.w;
        }
        __syncthreads();
        #pragma unroll 4
        for (int k = 0; k < KC; ++k) {
            int sw = SWZ(k);
            float2 xv  = *(const float2*)&xs[k][(ty * 2) ^ sw];
            int wc0 = (tx * 8) ^ sw;
            float4 wv0 = *(const float4*)&ws[k][wc0];
            float4 wv1 = *(const float4*)&ws[k][wc0 + 4];
            float xr[2] = {xv.x, xv.y};
            float wc[8] = {wv0.x, wv0.y, wv0.z, wv0.w, wv1.x, wv1.y, wv1.z, wv1.w};
            #pragma unroll
            for (int r = 0; r < 2; ++r)
                #pragma unroll
                for (int c = 0; c < 8; ++c)
                    acc[r][c] += xr[r] * wc[c];
        }
        __syncthreads();
    }

    // epilogue: fused as/ad from fp32 accumulators, fp16 H store
    float asv[8], adv[8];
    #pragma unroll
    for (int c = 0; c < 8; ++c) {
        asv[c] = a_src[tx * 8 + c];
        adv[c] = a_dst[tx * 8 + c];
    }
    #pragma unroll
    for (int r = 0; r < 2; ++r) {
        int gr = row0 + ty * 2 + r;
        float ps = 0.f, pd = 0.f;
        #pragma unroll
        for (int c = 0; c < 8; ++c) {
            ps += acc[r][c] * asv[c];
            pd += acc[r][c] * adv[c];
        }
        #pragma unroll
        for (int off = 8; off >= 1; off >>= 1) {   // reduce across 16 tx lanes
            ps += __shfl_xor(ps, off);
            pd += __shfl_xor(pd, off);
        }
        if (gr < nrows) {
            if (tx == 0) { as_[gr] = ps; ad_[gr] = pd; }
            __half2 hh[4];
            hh[0] = __floats2half2_rn(acc[r][0], acc[r][1]);
            hh[1] = __floats2half2_rn(acc[r][2], acc[r][3]);
            hh[2] = __floats2half2_rn(acc[r][4], acc[r][5]);
            hh[3] = __floats2half2_rn(acc[r][6], acc[r][7]);
            *(float4*)&H16[(size_t)gr * DD + tx * 8] = *(float4*)hh;
        }
    }
}

// ---------------- FAT kernel: layer-0 GEMM blocks + padded-CSR scatter blocks ----
__global__ __launch_bounds__(512, 6) void fat_kernel(
        int gemm_nblocks,
        const float* __restrict__ X, const float* __restrict__ W,
        const float* __restrict__ a_src, const float* __restrict__ a_dst,
        __half* __restrict__ H16, float* __restrict__ as_, float* __restrict__ ad_,
        int nrows,
        const int* __restrict__ esrc, const int* __restrict__ edst,
        int* __restrict__ cursor, int* __restrict__ csr_p) {
    __shared__ float xs[KC][XS_LD];
    __shared__ float ws[KC][WS_LD];
    if ((int)blockIdx.x >= gemm_nblocks) {
        int i = (blockIdx.x - gemm_nblocks) * 512 + threadIdx.x;
        if (i < NE) {
            int d = edst[i];
            int k = atomicAdd(&cursor[d << 4], 1);
            if (k < CAP) csr_p[(d << 6) + k] = esrc[i];
        }
        return;
    }
    gemm_body(X, W, a_src, a_dst, H16, as_, ad_, nrows, blockIdx.x * BM, xs, ws);
}

// ---------------- standalone GEMM (layers 1,2) ----------------
__global__ __launch_bounds__(512, 6) void gemm_xwt(
        const float* __restrict__ X, const float* __restrict__ W,
        const float* __restrict__ a_src, const float* __restrict__ a_dst,
        __half* __restrict__ H16, float* __restrict__ as_, float* __restrict__ ad_,
        int nrows) {
    __shared__ float xs[KC][XS_LD];
    __shared__ float ws[KC][WS_LD];
    gemm_body(X, W, a_src, a_dst, H16, as_, ad_, nrows, blockIdx.x * BM, xs, ws);
}

__device__ inline void xr4s(float4& a, int off) {
    a.x += __shfl_xor(a.x, off);
    a.y += __shfl_xor(a.y, off);
    a.z += __shfl_xor(a.z, off);
    a.w += __shfl_xor(a.w, off);
}
// accumulate one fp16 16B chunk (8 halfs) into two float4 accs
__device__ inline void fma_h8(float4& a0, float4& a1, float p, const float4& raw) {
    const __half2* q = (const __half2*)&raw;
    float2 c;
    c = __half22float2(q[0]); a0.x += p * c.x; a0.y += p * c.y;
    c = __half22float2(q[1]); a0.z += p * c.x; a0.w += p * c.y;
    c = __half22float2(q[2]); a1.x += p * c.x; a1.y += p * c.y;
    c = __half22float2(q[3]); a1.z += p * c.x; a1.w += p * c.y;
}

// ---------------- dst-centric aggregation on padded CSR, fp16 gather ----------------
// Phase 1: lane j = edge j -> m, l, p_j, s_j in LDS (once).
// Phase 2: outer loop over row halves (chunks 0-7, then 8-15);
//          8 groups x 8 lanes, 2 edge streams -> 16 edges / 2 loads-per-lane in flight.
__global__ __launch_bounds__(256) void gat_agg_kernel(
        const __half* __restrict__ H16, const float* __restrict__ as_,
        const float* __restrict__ ad_, const int* __restrict__ cursor,
        const int* __restrict__ csr_p, float* __restrict__ Y, int apply_lrelu) {
    __shared__ float p_sh[4][64];
    __shared__ int   s_sh[4][64];
    int wid  = threadIdx.x >> 6;
    int node = blockIdx.x * 4 + wid;        // NN % 4 == 0: always valid
    int lane = threadIdx.x & 63;
    int deg_r = min(cursor[node << 4], CAP);
    int deg = deg_r + 1;                    // + implicit self loop
    float adn = ad_[node];

    float e = -1e30f;
    if (lane < deg) {
        int s = (lane == deg_r) ? node : csr_p[(node << 6) + lane];
        s_sh[wid][lane] = s;
        float ev = as_[s] + adn;
        e = (ev > 0.f) ? ev : NSA * ev;
    }
    float m = e;
    #pragma unroll
    for (int off = 32; off >= 1; off >>= 1) m = fmaxf(m, __shfl_xor(m, off));
    float pv = 0.f;
    if (lane < deg) {
        pv = __expf(e - m);
        p_sh[wid][lane] = pv;
    }
    float l = pv;
    #pragma unroll
    for (int off = 32; off >= 1; off >>= 1) l += __shfl_xor(l, off);
    __builtin_amdgcn_wave_barrier();   // LDS p/s now valid wave-wide

    int g  = lane >> 3;                // edge group 0..7
    int d8 = lane & 7;                 // chunk-within-half
    const float4* H4 = (const float4*)H16;   // 16 x 16B chunks per row
    float inv = 1.f / (l + EPS);

    #pragma unroll
    for (int h = 0; h < 2; ++h) {
        int chunk = h * 8 + d8;
        float4 a0 = {0,0,0,0}, a1 = {0,0,0,0};   // stream A (dims chunk*8..+7)
        float4 b0 = {0,0,0,0}, b1 = {0,0,0,0};   // stream B
        for (int j = g; j < deg; j += 16) {
            int   s0 = s_sh[wid][j];
            float p0 = p_sh[wid][j];
            int   j1 = j + 8;
            bool  v1 = j1 < deg;
            int   s1 = v1 ? s_sh[wid][j1] : s0;
            float p1 = v1 ? p_sh[wid][j1] : 0.f;
            float4 raw0 = H4[(size_t)s0 * 16 + chunk];
            float4 raw1 = H4[(size_t)s1 * 16 + chunk];
            fma_h8(a0, a1, p0, raw0);
            fma_h8(b0, b1, p1, raw1);
        }
        a0.x += b0.x; a0.y += b0.y; a0.z += b0.z; a0.w += b0.w;
        a1.x += b1.x; a1.y += b1.y; a1.z += b1.z; a1.w += b1.w;
        xr4s(a0, 8); xr4s(a0, 16); xr4s(a0, 32);
        xr4s(a1, 8); xr4s(a1, 16); xr4s(a1, 32);
        if (g == 0) {
            float4 o0, o1;
            o0.x = a0.x * inv; o0.y = a0.y * inv; o0.z = a0.z * inv; o0.w = a0.w * inv;
            o1.x = a1.x * inv; o1.y = a1.y * inv; o1.z = a1.z * inv; o1.w = a1.w * inv;
            if (apply_lrelu) {
                o0.x = (o0.x > 0.f) ? o0.x : NSB * o0.x;
                o0.y = (o0.y > 0.f) ? o0.y : NSB * o0.y;
                o0.z = (o0.z > 0.f) ? o0.z : NSB * o0.z;
                o0.w = (o0.w > 0.f) ? o0.w : NSB * o0.w;
                o1.x = (o1.x > 0.f) ? o1.x : NSB * o1.x;
                o1.y = (o1.y > 0.f) ? o1.y : NSB * o1.y;
                o1.z = (o1.z > 0.f) ? o1.z : NSB * o1.z;
                o1.w = (o1.w > 0.f) ? o1.w : NSB * o1.w;
            }
            *(float4*)&Y[(size_t)node * DD + chunk * 8]     = o0;
            *(float4*)&Y[(size_t)node * DD + chunk * 8 + 4] = o1;
        }
    }
}

// ---------------- global_add_pool over sorted batch ----------------
__global__ void pool_kernel(const float* __restrict__ Y, const int* __restrict__ batch,
                            float* __restrict__ out) {
    int w = blockIdx.x * 4 + (threadIdx.x >> 6);
    int lane = threadIdx.x & 63;
    int n0 = w * 32;
    if (n0 >= NN) return;
    int n1 = min(n0 + 32, NN);
    const float2* Y2 = (const float2*)Y;
    float2 acc = {0.f, 0.f};
    int g = batch[n0];
    for (int n = n0; n < n1; ++n) {
        int gn = batch[n];
        if (gn != g) {
            atomicAdd(&out[g * DD + 2 * lane], acc.x);
            atomicAdd(&out[g * DD + 2 * lane + 1], acc.y);
            acc.x = 0.f; acc.y = 0.f;
            g = gn;
        }
        float2 v = Y2[n * 64 + lane];
        acc.x += v.x; acc.y += v.y;
    }
    atomicAdd(&out[g * DD + 2 * lane], acc.x);
    atomicAdd(&out[g * DD + 2 * lane + 1], acc.y);
}

extern "C" void kernel_launch(void* const* d_in, const int* in_sizes, int n_in,
                              void* d_out, int out_size, void* d_ws, size_t ws_size,
                              hipStream_t stream) {
    const float* x      = (const float*)d_in[0];
    const int*   ei     = (const int*)d_in[1];
    const int*   batch  = (const int*)d_in[2];
    const int*   src    = ei;
    const int*   dst    = ei + NE;
    float* out = (float*)d_out;

    size_t off = 0;
    auto carve = [&](size_t bytes) {
        void* p = (char*)d_ws + off;
        off += (bytes + 255) & ~(size_t)255;
        return p;
    };
    __half* h16   = (__half*)carve((size_t)NN * DD * 2);      // 12.8 MB fp16 features
    float*  y     = (float*)carve((size_t)NN * DD * 4);       // 25.6 MB fp32 layer out
    float*  as_   = (float*)carve((size_t)NN * 4);
    float*  ad_   = (float*)carve((size_t)NN * 4);
    int*    cursor= (int*)carve((size_t)NN * 16 * 4);         // 64B-strided counters
    int*    csr_p = (int*)carve((size_t)NN * 64 * 4);         // 12.8 MB padded CSR

    const int gemm_blocks = (NN + BM - 1) / BM;      // 782
    const int scat_blocks = (NE + 511) / 512;        // 1563
    const int node_blocks = (NN + 3) / 4;            // 12500
    const int init_blocks = (NN * 16 + 255) / 256;   // 3125

    const float* W0  = (const float*)d_in[3];
    const float* av0 = (const float*)d_in[4];
    const float* ad0 = (const float*)d_in[5];

    // ---- init + (full gemm0 || padded-CSR scatter) ----
    init_kernel<<<init_blocks, 256, 0, stream>>>(cursor, out);
    fat_kernel<<<gemm_blocks + scat_blocks, 512, 0, stream>>>(
        gemm_blocks, x, W0, av0, ad0, h16, as_, ad_, NN, src, dst, cursor, csr_p);

    // ---- layer 0 aggregation, then layers 1,2 ----
    gat_agg_kernel<<<node_blocks, 256, 0, stream>>>(h16, as_, ad_, cursor, csr_p, y, 0);
    for (int L = 1; L < 3; ++L) {
        const float* W  = (const float*)d_in[3 + 3 * L];
        const float* av = (const float*)d_in[4 + 3 * L];
        const float* ad = (const float*)d_in[5 + 3 * L];
        gemm_xwt<<<gemm_blocks, 512, 0, stream>>>(y, W, av, ad, h16, as_, ad_, NN);
        gat_agg_kernel<<<node_blocks, 256, 0, stream>>>(h16, as_, ad_, cursor, csr_p, y,
                                                        (L == 1) ? 1 : 0);
    }

    // ---- pool ----
    const int pool_blocks = ((NN + 31) / 32 + 3) / 4;
    pool_kernel<<<pool_blocks, 256, 0, stream>>>(y, batch, out);
}